// Round 17
// baseline (78.781 us; speedup 1.0000x reference)
//
#include <hip/hip_runtime.h>
#include <hip/hip_bf16.h>

#define TDIM 1024
#define KDIM 32

typedef short bf16x8 __attribute__((ext_vector_type(8)));
typedef float f32x4  __attribute__((ext_vector_type(4)));
typedef float f32x2  __attribute__((ext_vector_type(2)));

// RNE-ish pack (round-half-up): 3 VALU. Off the hot loop only.
__device__ __forceinline__ unsigned pk_pair(float lo, float hi) {
    unsigned ul = __float_as_uint(lo) + 0x8000u;
    unsigned uh = __float_as_uint(hi) + 0x8000u;
    return __builtin_amdgcn_perm(uh, ul, 0x07060302u);
}
// truncating pack: 1 VALU. Hot loop (bias ~-0.1%/use; ledger-safe, R14-verified).
__device__ __forceinline__ unsigned tk_pair(float lo, float hi) {
    return __builtin_amdgcn_perm(__float_as_uint(hi), __float_as_uint(lo), 0x07060302u);
}
__device__ __forceinline__ bf16x8 pk8(f32x4 lo, f32x4 hi) {
    union { unsigned u[4]; bf16x8 v; } x;
    x.u[0] = pk_pair(lo[0], lo[1]); x.u[1] = pk_pair(lo[2], lo[3]);
    x.u[2] = pk_pair(hi[0], hi[1]); x.u[3] = pk_pair(hi[2], hi[3]);
    return x.v;
}
__device__ __forceinline__ bf16x8 tk8(f32x4 lo, f32x4 hi) {
    union { unsigned u[4]; bf16x8 v; } x;
    x.u[0] = tk_pair(lo[0], lo[1]); x.u[1] = tk_pair(lo[2], lo[3]);
    x.u[2] = tk_pair(hi[0], hi[1]); x.u[3] = tk_pair(hi[2], hi[3]);
    return x.v;
}
__device__ __forceinline__ f32x4 dmul(f32x4 c, f32x4 e) {
    union U { f32x4 v; f32x2 h[2]; };
    U uc, ue, r; uc.v = c; ue.v = e;
    r.h[0] = uc.h[0] * ue.h[0];
    r.h[1] = uc.h[1] * ue.h[1];
    return r.v;
}
__device__ __forceinline__ f32x4 dscale(f32x4 c, float s) {
    union U { f32x4 v; f32x2 h[2]; };
    U uc, r; uc.v = c;
    f32x2 sv = {s, s};
    r.h[0] = uc.h[0] * sv;
    r.h[1] = uc.h[1] * sv;
    return r.v;
}

__device__ __forceinline__ int read_len(const int* __restrict__ lengths32, int b) {
    // int64 little-endian: int32 view at odd index 1 is high word of lengths[0] == 0.
    // int32: lengths[1] in [1,1024], never 0.  (verified rounds 1-16)
    const bool is64 = (lengths32[1] == 0);
    int len = is64 ? lengths32[2 * b] : lengths32[b];
    return len < 1 ? 1 : (len > TDIM ? TDIM : len);
}

// ---------------- K1: dual-chain, lean-step chunk kernel ------------------
// Wave w owns adjacent chunks (2w, 2w+1). Per chain-step (R14's lean body):
// B = trunc-pack(d (.) C) = 8 mul + 8 perm, 4 MFMA, A static. The second
// chain's work fills the first chain's MFMA->VALU readback latency (R16
// diagnosis: per-wave latency-bound, both pipes ~80% idle at 1.1 waves/SIMD).
template<int CHS, int NCH, int WPB>
__global__ __launch_bounds__(64 * WPB) void crf_chunk_dual(
    const float* __restrict__ emissions,    // [B, T, K]
    const int*   __restrict__ lengths32,
    const float* __restrict__ transitions,  // [K, K]
    unsigned int* __restrict__ Pout,        // [B][NCH][1024] bf16 as 512 dwords
    int*          __restrict__ toteOut)     // [B][NCH]
{
    constexpr int NSEG = CHS * KDIM / 256;   // 1KB DMA segments per chain
    __shared__ float lds_all[WPB][2][CHS * KDIM];
    const int wid  = threadIdx.x >> 6;
    const int lane = threadIdx.x & 63;
    const int n    = lane & 15;
    const int g    = (lane >> 4) & 3;
    const int w    = blockIdx.x * WPB + wid;
    const int b    = blockIdx.y;
    const int cA   = 2 * w, cB = 2 * w + 1;

    const int len = read_len(lengths32, b);
    const int tsA = 1 + cA * CHS, tsB = tsA + CHS;
    int cntA = len - tsA; cntA = cntA > CHS ? CHS : cntA;
    if (cntA <= 0) return;                    // adjacent pairing: cntB <= cntA
    int cntB = len - tsB; cntB = cntB > CHS ? CHS : cntB; if (cntB < 0) cntB = 0;
    const int shfB = (tsB + CHS > TDIM) ? (tsB - (TDIM - CHS)) : 0;  // {0,1}

    float* slA = &lds_all[wid][0][0];
    float* slB = &lds_all[wid][1][0];

    {   // DMA chain A
        const float* src = emissions + ((size_t)b * TDIM + tsA) * KDIM;
#pragma unroll
        for (int s = 0; s < NSEG; ++s)
            __builtin_amdgcn_global_load_lds(
                (const __attribute__((address_space(1))) void*)(src + s * 256 + lane * 4),
                (__attribute__((address_space(3))) void*)(slA + s * 256), 16, 0, 0);
    }
    if (cntB > 0) {  // DMA chain B
        const float* src = emissions + ((size_t)b * TDIM + (tsB - shfB)) * KDIM;
#pragma unroll
        for (int s = 0; s < NSEG; ++s)
            __builtin_amdgcn_global_load_lds(
                (const __attribute__((address_space(1))) void*)(src + s * 256 + lane * 4),
                (__attribute__((address_space(3))) void*)(slB + s * 256), 16, 0, 0);
    }

    // static A operand: bf16(E^T), shared by both chains
    f32x4 Ef00, Ef01, Ef10, Ef11;
#pragma unroll
    for (int e = 0; e < 4; ++e) {
        Ef00[e] = __expf(transitions[(4 * g + e) * KDIM + n]);
        Ef01[e] = __expf(transitions[(16 + 4 * g + e) * KDIM + n]);
        Ef10[e] = __expf(transitions[(4 * g + e) * KDIM + 16 + n]);
        Ef11[e] = __expf(transitions[(16 + 4 * g + e) * KDIM + 16 + n]);
    }
    const bf16x8 A0 = pk8(Ef00, Ef01);
    const bf16x8 A1 = pk8(Ef10, Ef11);

    asm volatile("s_waitcnt vmcnt(0)" ::: "memory");
    __builtin_amdgcn_sched_barrier(0);

    // exp pre-pass over both slices (dead-B garbage harmless, in-bounds)
    f32x4* mvAll = (f32x4*)slA;   // [2][CHS*KDIM] contiguous per wave
#pragma unroll
    for (int r = 0; r < 2 * NSEG; ++r) {
        f32x4 v = mvAll[r * 64 + lane];
#pragma unroll
        for (int e = 0; e < 4; ++e) v[e] = __expf(v[e]);
        mvAll[r * 64 + lane] = v;
    }
    asm volatile("s_waitcnt lgkmcnt(0)" ::: "memory");
    __builtin_amdgcn_sched_barrier(0);

    const f32x4* mvA = (const f32x4*)slA;
    const f32x4* mvB = (const f32x4*)slB;

    f32x4 CA0, CA1, CA2, CA3, CB0, CB1, CB2, CB3;
#pragma unroll
    for (int q = 0; q < 4; ++q) {
        float d = (4 * g + q == n) ? 1.0f : 0.0f;
        CA0[q] = d; CA3[q] = d; CA1[q] = 0.0f; CA2[q] = 0.0f;
        CB0[q] = d; CB3[q] = d; CB1[q] = 0.0f; CB2[q] = 0.0f;
    }
    float sfA = 1.0f, sfB = 1.0f;
    int pendA = 0, pendB = 0, toteA = 0, toteB = 0;
    const f32x4 zero = {0.0f, 0.0f, 0.0f, 0.0f};

    auto LDE = [&](const f32x4* mv, int tt, int shf, f32x4& e0, f32x4& e1) {
        tt += shf; if (tt > CHS - 1) tt = CHS - 1;
        e0 = mv[tt * 8 + g];
        e1 = mv[tt * 8 + 4 + g];
    };
    // lean step (R14): 8 pk-mul + 8 perm + 4 MFMA; A static
    auto STEPC = [&](f32x4& c0, f32x4& c1, f32x4& c2, f32x4& c3,
                     const f32x4& e0, const f32x4& e1) {
        f32x4 t0v = dmul(c0, e0), t1v = dmul(c2, e1);
        f32x4 t2v = dmul(c1, e0), t3v = dmul(c3, e1);
        bf16x8 B0 = tk8(t0v, t1v), B1 = tk8(t2v, t3v);
        c0 = __builtin_amdgcn_mfma_f32_16x16x32_bf16(A0, B0, zero, 0, 0, 0);
        c1 = __builtin_amdgcn_mfma_f32_16x16x32_bf16(A0, B1, zero, 0, 0, 0);
        c2 = __builtin_amdgcn_mfma_f32_16x16x32_bf16(A1, B0, zero, 0, 0, 0);
        c3 = __builtin_amdgcn_mfma_f32_16x16x32_bf16(A1, B1, zero, 0, 0, 0);
    };
    auto FOLD = [&](f32x4& e0, f32x4& e1, float sf, int& tote, int pend) {
        e0 = dscale(e0, sf);
        e1 = dscale(e1, sf);
        tote += pend;
    };
    auto RESC = [&](const f32x4& c0, float& sf, int& pend) {
        int bits = __builtin_amdgcn_readfirstlane(__float_as_int(c0[0]));
        pend = ((bits >> 23) & 255) - 127;
        sf = __uint_as_float((unsigned)(127 - pend) << 23);
    };

    f32x4 eA0, eA1, eB0, eB1, nA0, nA1, nB0, nB1;
    LDE(mvA, 0, 0, eA0, eA1);
    if (cntB > 0) LDE(mvB, 0, shfB, eB0, eB1);

    if (cntB > 0) {                   // A is full (cntA == CHS)
        const int kg = cntB >> 2;     // joint full groups
        for (int gq = 0; gq < kg; ++gq) {
#pragma unroll
            for (int u = 0; u < 4; ++u) {
                const int tau = 4 * gq + u;
                LDE(mvA, tau + 1, 0,    nA0, nA1);
                LDE(mvB, tau + 1, shfB, nB0, nB1);
                if (u == 0) {
                    FOLD(eA0, eA1, sfA, toteA, pendA);
                    FOLD(eB0, eB1, sfB, toteB, pendB);
                }
                STEPC(CA0, CA1, CA2, CA3, eA0, eA1);
                STEPC(CB0, CB1, CB2, CB3, eB0, eB1);
                if (u == 3) { RESC(CA0, sfA, pendA); RESC(CB0, sfB, pendB); }
                eA0 = nA0; eA1 = nA1; eB0 = nB0; eB1 = nB1;
            }
        }
        for (int gq = kg; gq < CHS / 4; ++gq) {   // A-only remaining groups
#pragma unroll
            for (int u = 0; u < 4; ++u) {
                const int tau = 4 * gq + u;
                LDE(mvA, tau + 1, 0, nA0, nA1);
                if (u == 0) FOLD(eA0, eA1, sfA, toteA, pendA);
                STEPC(CA0, CA1, CA2, CA3, eA0, eA1);
                if (u == 3) RESC(CA0, sfA, pendA);
                eA0 = nA0; eA1 = nA1;
            }
        }
        for (int tau = kg * 4; tau < cntB; ++tau) {  // B tail, per-step cadence
            LDE(mvB, tau + 1, shfB, nB0, nB1);
            FOLD(eB0, eB1, sfB, toteB, pendB);
            STEPC(CB0, CB1, CB2, CB3, eB0, eB1);
            RESC(CB0, sfB, pendB);
            eB0 = nB0; eB1 = nB1;
        }
    } else {                          // A-only, possibly partial
        const int fg = cntA >> 2;
        for (int gq = 0; gq < fg; ++gq) {
#pragma unroll
            for (int u = 0; u < 4; ++u) {
                const int tau = 4 * gq + u;
                LDE(mvA, tau + 1, 0, nA0, nA1);
                if (u == 0) FOLD(eA0, eA1, sfA, toteA, pendA);
                STEPC(CA0, CA1, CA2, CA3, eA0, eA1);
                if (u == 3) RESC(CA0, sfA, pendA);
                eA0 = nA0; eA1 = nA1;
            }
        }
        for (int tau = fg * 4; tau < cntA; ++tau) {
            LDE(mvA, tau + 1, 0, nA0, nA1);
            FOLD(eA0, eA1, sfA, toteA, pendA);
            STEPC(CA0, CA1, CA2, CA3, eA0, eA1);
            RESC(CA0, sfA, pendA);
            eA0 = nA0; eA1 = nA1;
        }
    }

    // store: bf16 col-major, dword idx = col*16 + row/2 (RNE pack, once)
    auto STORE = [&](unsigned int* outP, const f32x4& c0, const f32x4& c1,
                     const f32x4& c2, const f32x4& c3) {
#pragma unroll
        for (int p = 0; p < 2; ++p) {
            int q = 2 * p;
            outP[n * 16        + (4 * g + q) / 2]      = pk_pair(c0[q], c0[q + 1]);
            outP[(16 + n) * 16 + (4 * g + q) / 2]      = pk_pair(c1[q], c1[q + 1]);
            outP[n * 16        + (16 + 4 * g + q) / 2] = pk_pair(c2[q], c2[q + 1]);
            outP[(16 + n) * 16 + (16 + 4 * g + q) / 2] = pk_pair(c3[q], c3[q + 1]);
        }
    };
    STORE(Pout + ((size_t)b * NCH + cA) * 512, CA0, CA1, CA2, CA3);
    if (lane == 0) toteOut[b * NCH + cA] = toteA;
    if (cntB > 0) {
        STORE(Pout + ((size_t)b * NCH + cB) * 512, CB0, CB1, CB2, CB3);
        if (lane == 0) toteOut[b * NCH + cB] = toteB;
    }
}

// ---------------- K2: chain chunk matrices through alpha ------------------
template<int NCH, int CHS>
__global__ __launch_bounds__(64) void crf_combine_kernel(
    const float* __restrict__ emissions,
    const int*   __restrict__ lengths32,
    const float* __restrict__ head_t,
    const float* __restrict__ last_t,
    const unsigned short* __restrict__ Pbuf,  // [B][NCH][1024] bf16 col-major
    const int*   __restrict__ toteBuf,
    float*       __restrict__ out)
{
    const int b    = blockIdx.x;
    const int lane = threadIdx.x;
    const int j    = lane & 31;

    const int len = read_len(lengths32, b);
    int nAlive = (len - 1 + CHS - 1) / CHS;
    if (nAlive > NCH) nAlive = NCH;

    float alpha = __expf(head_t[j] + emissions[(size_t)b * TDIM * KDIM + j]);
    int tote = 0;

    const char* base = (const char*)(Pbuf + (size_t)b * NCH * 1024);

    auto LOADC = [&](int cix, uint4 dst[4]) {
        int cc = cix < NCH ? cix : NCH - 1;
        const uint4* pc = (const uint4*)(base + (size_t)cc * 2048 + (size_t)j * 64);
#pragma unroll
        for (int w = 0; w < 4; ++w) dst[w] = pc[w];
    };

    uint4 cur[4], nx1[4];
    LOADC(0, cur);
    LOADC(1, nx1);

    for (int cix = 0; cix < nAlive; ++cix) {
        uint4 nx2[4];
        LOADC(cix + 2, nx2);

        float a0 = 0.0f, a1 = 0.0f;
#pragma unroll
        for (int w = 0; w < 4; ++w) {
            unsigned d[4] = {cur[w].x, cur[w].y, cur[w].z, cur[w].w};
#pragma unroll
            for (int h = 0; h < 4; ++h) {
                int r = w * 8 + h * 2;
                float plo = __uint_as_float(d[h] << 16);           // row r,   col j
                float phi = __uint_as_float(d[h] & 0xffff0000u);   // row r+1, col j
                float al  = __int_as_float(__builtin_amdgcn_readlane(__float_as_int(alpha), r));
                float ah  = __int_as_float(__builtin_amdgcn_readlane(__float_as_int(alpha), r + 1));
                a0 = fmaf(plo, al, a0);
                a1 = fmaf(phi, ah, a1);
            }
        }
        float acc = a0 + a1;
        int bits = __builtin_amdgcn_readfirstlane(__float_as_int(acc));
        int s = ((bits >> 23) & 255) - 127;
        alpha = acc * __uint_as_float((unsigned)(127 - s) << 23);
        tote += s + toteBuf[b * NCH + cix];
#pragma unroll
        for (int w = 0; w < 4; ++w) { cur[w] = nx1[w]; nx1[w] = nx2[w]; }
    }

    float pp = alpha * __expf(last_t[j]);
#pragma unroll
    for (int mm = 16; mm >= 1; mm >>= 1)
        pp += __shfl_xor(pp, mm, 64);

    if (lane == 0)
        out[b] = __logf(pp) + (float)tote * 0.69314718055994531f;
}

extern "C" void kernel_launch(void* const* d_in, const int* in_sizes, int n_in,
                              void* d_out, int out_size, void* d_ws, size_t ws_size,
                              hipStream_t stream)
{
    const float* emissions   = (const float*)d_in[0];
    const int*   lengths     = (const int*)d_in[1];
    const float* transitions = (const float*)d_in[2];
    const float* head_t      = (const float*)d_in[3];
    const float* last_t      = (const float*)d_in[4];
    float* out = (float*)d_out;
    const int B = out_size;  // 512

    unsigned int* Pbuf = (unsigned int*)d_ws;

    const size_t need16 = (size_t)B * 16 * 2048 + (size_t)B * 16 * 4;
    if (ws_size >= need16) {
        int* toteBf = (int*)((char*)d_ws + (size_t)B * 16 * 2048);
        // CHS=64, NCH=16, 2 chains/wave, 2 waves/block (32KB LDS, 5 blk/CU):
        // 8 pairs/batch -> grid.x = 4
        dim3 g1(4, B);
        crf_chunk_dual<64, 16, 2><<<g1, 128, 0, stream>>>(emissions, lengths, transitions, Pbuf, toteBf);
        crf_combine_kernel<16, 64><<<B, 64, 0, stream>>>(emissions, lengths, head_t, last_t,
                                                         (const unsigned short*)Pbuf, toteBf, out);
    } else {
        int* toteBf = (int*)((char*)d_ws + (size_t)B * 8 * 2048);
        dim3 g1(2, B);   // 4 pairs/batch, 2 waves/block
        crf_chunk_dual<128, 8, 2><<<g1, 128, 0, stream>>>(emissions, lengths, transitions, Pbuf, toteBf);
        crf_combine_kernel<8, 128><<<B, 64, 0, stream>>>(emissions, lengths, head_t, last_t,
                                                         (const unsigned short*)Pbuf, toteBf, out);
    }
}

// Round 18
// 54.843 us; speedup vs baseline: 1.4365x; 1.4365x over previous
//
#include <hip/hip_runtime.h>
#include <hip/hip_bf16.h>

#define TDIM 1024
#define KDIM 32

typedef short bf16x8 __attribute__((ext_vector_type(8)));
typedef float f32x4  __attribute__((ext_vector_type(4)));
typedef float f32x2  __attribute__((ext_vector_type(2)));

// RNE-ish pack (round-half-up): 3 VALU. Off the hot loop only.
__device__ __forceinline__ unsigned pk_pair(float lo, float hi) {
    unsigned ul = __float_as_uint(lo) + 0x8000u;
    unsigned uh = __float_as_uint(hi) + 0x8000u;
    return __builtin_amdgcn_perm(uh, ul, 0x07060302u);
}
// truncating pack: 1 VALU. Hot loop (bias ~-0.1%/use; ledger-safe, R14-verified).
__device__ __forceinline__ unsigned tk_pair(float lo, float hi) {
    return __builtin_amdgcn_perm(__float_as_uint(hi), __float_as_uint(lo), 0x07060302u);
}
__device__ __forceinline__ bf16x8 pk8(f32x4 lo, f32x4 hi) {
    union { unsigned u[4]; bf16x8 v; } x;
    x.u[0] = pk_pair(lo[0], lo[1]); x.u[1] = pk_pair(lo[2], lo[3]);
    x.u[2] = pk_pair(hi[0], hi[1]); x.u[3] = pk_pair(hi[2], hi[3]);
    return x.v;
}
__device__ __forceinline__ bf16x8 tk8(f32x4 lo, f32x4 hi) {
    union { unsigned u[4]; bf16x8 v; } x;
    x.u[0] = tk_pair(lo[0], lo[1]); x.u[1] = tk_pair(lo[2], lo[3]);
    x.u[2] = tk_pair(hi[0], hi[1]); x.u[3] = tk_pair(hi[2], hi[3]);
    return x.v;
}
// f32 elementwise muls as <2 x float> so ISel can form v_pk_mul_f32
__device__ __forceinline__ f32x4 dmul(f32x4 c, f32x4 e) {
    union U { f32x4 v; f32x2 h[2]; };
    U uc, ue, r; uc.v = c; ue.v = e;
    r.h[0] = uc.h[0] * ue.h[0];
    r.h[1] = uc.h[1] * ue.h[1];
    return r.v;
}
__device__ __forceinline__ f32x4 dscale(f32x4 c, float s) {
    union U { f32x4 v; f32x2 h[2]; };
    U uc, r; uc.v = c;
    f32x2 sv = {s, s};
    r.h[0] = uc.h[0] * sv;
    r.h[1] = uc.h[1] * sv;
    return r.v;
}

__device__ __forceinline__ int read_len(const int* __restrict__ lengths32, int b) {
    // int64 little-endian: int32 view at odd index 1 is high word of lengths[0] == 0.
    // int32: lengths[1] in [1,1024], never 0.  (verified rounds 1-17)
    const bool is64 = (lengths32[1] == 0);
    int len = is64 ? lengths32[2 * b] : lengths32[b];
    return len < 1 ? 1 : (len > TDIM ? TDIM : len);
}

// ---------------- K1: per-(batch, chunk) 32x32 product matrix -------------
// SHORT-CHAIN + LEAN (R6 algebra, R14 packs): fold D_t into the A operand
// (A_t = trunc-pack(Ef (.) d), emission-only -> OFF the dependency chain);
// B = trunc-pack(previous C) -> the MFMA->MFMA chain contains ONLY 8 perms.
// ~28 VALU/step total.
template<int CHS, int NCH>
__global__ __launch_bounds__(256, 4) void crf_chunk_kernel(
    const float* __restrict__ emissions,    // [B, T, K]
    const int*   __restrict__ lengths32,
    const float* __restrict__ transitions,  // [K, K]
    unsigned int* __restrict__ Pout,        // [B][NCH][1024] bf16 as 512 dwords
    int*          __restrict__ toteOut)     // [B][NCH]
{
    __shared__ float lds_all[4][CHS * KDIM];
    const int wid  = threadIdx.x >> 6;
    const int lane = threadIdx.x & 63;
    const int n    = lane & 15;
    const int g    = (lane >> 4) & 3;
    const int c    = blockIdx.x * 4 + wid;
    const int b    = blockIdx.y;

    const int len = read_len(lengths32, b);
    const int t0  = 1 + c * CHS;
    int count = len - t0; count = count > CHS ? CHS : count;
    if (count <= 0) return;                  // dead chunk

    // ---- stage CHS emission rows into this wave's LDS slice (async DMA) ----
    int base_t = t0, shift = 0;
    if (t0 + CHS > TDIM) { base_t = TDIM - CHS; shift = t0 - base_t; }
    const float* src = emissions + ((size_t)b * TDIM + base_t) * KDIM;
    float* myl = lds_all[wid];
    constexpr int NSEG = CHS * KDIM / 256;   // 1KB segments
#pragma unroll
    for (int s = 0; s < NSEG; ++s)
        __builtin_amdgcn_global_load_lds(
            (const __attribute__((address_space(1))) void*)(src + s * 256 + lane * 4),
            (__attribute__((address_space(3))) void*)(myl + s * 256), 16, 0, 0);

    // static E^T factors in f32 (A elem e <-> contraction row rho(g,e))
    f32x4 Ef00, Ef01, Ef10, Ef11;
#pragma unroll
    for (int e = 0; e < 4; ++e) {
        Ef00[e] = __expf(transitions[(4 * g + e) * KDIM + n]);
        Ef01[e] = __expf(transitions[(16 + 4 * g + e) * KDIM + n]);
        Ef10[e] = __expf(transitions[(4 * g + e) * KDIM + 16 + n]);
        Ef11[e] = __expf(transitions[(16 + 4 * g + e) * KDIM + 16 + n]);
    }

    asm volatile("s_waitcnt vmcnt(0)" ::: "memory");
    __builtin_amdgcn_sched_barrier(0);

    // ---- exp pre-pass in place (per-wave slice) ----
    f32x4* mylv = (f32x4*)myl;
#pragma unroll
    for (int r = 0; r < NSEG; ++r) {
        f32x4 v = mylv[r * 64 + lane];
#pragma unroll
        for (int e = 0; e < 4; ++e) v[e] = __expf(v[e]);
        mylv[r * 64 + lane] = v;
    }
    asm volatile("s_waitcnt lgkmcnt(0)" ::: "memory");
    __builtin_amdgcn_sched_barrier(0);

    // ---- running product in C-frags ----
    f32x4 C00, C01, C10, C11;
#pragma unroll
    for (int q = 0; q < 4; ++q) {
        float d = (4 * g + q == n) ? 1.0f : 0.0f;
        C00[q] = d; C11[q] = d; C01[q] = 0.0f; C10[q] = 0.0f;
    }
    float sf = 1.0f; int pend = 0, tote = 0;
    const f32x4 zero = {0.0f, 0.0f, 0.0f, 0.0f};

    // A_t = trunc-pack(Ef (.) d)   (emission-only, off the MFMA chain)
    // B   = trunc-pack(previous C) (the ONLY ops on the MFMA->MFMA chain)
    auto STEP = [&](const f32x4& e0, const f32x4& e1) {
        f32x4 a00 = dmul(Ef00, e0), a01 = dmul(Ef01, e1);
        f32x4 a10 = dmul(Ef10, e0), a11 = dmul(Ef11, e1);
        bf16x8 A0 = tk8(a00, a01), A1 = tk8(a10, a11);
        bf16x8 B0 = tk8(C00, C10), B1 = tk8(C01, C11);
        C00 = __builtin_amdgcn_mfma_f32_16x16x32_bf16(A0, B0, zero, 0, 0, 0);
        C01 = __builtin_amdgcn_mfma_f32_16x16x32_bf16(A0, B1, zero, 0, 0, 0);
        C10 = __builtin_amdgcn_mfma_f32_16x16x32_bf16(A1, B0, zero, 0, 0, 0);
        C11 = __builtin_amdgcn_mfma_f32_16x16x32_bf16(A1, B1, zero, 0, 0, 0);
    };
    auto RESCALE = [&]() {
        int bits = __builtin_amdgcn_readfirstlane(__float_as_int(C00[0]));
        pend = ((bits >> 23) & 255) - 127;
        sf = __uint_as_float((unsigned)(127 - pend) << 23);
    };

    if (count == CHS) {
        // depth-2 LDS read pipeline, static slot = u&1
        f32x4 pipe[2][2];
        pipe[0][0] = mylv[0 * 8 + g]; pipe[0][1] = mylv[0 * 8 + 4 + g];
        pipe[1][0] = mylv[1 * 8 + g]; pipe[1][1] = mylv[1 * 8 + 4 + g];
        constexpr int NQ = CHS / 4;
        for (int tq = 0; tq < NQ; ++tq) {
#pragma unroll
            for (int u = 0; u < 4; ++u) {
                const int s = u & 1;
                f32x4 e0 = pipe[s][0], e1 = pipe[s][1];
                int tl = 4 * tq + u + 2; if (tl > CHS - 1) tl = CHS - 1;
                pipe[s][0] = mylv[tl * 8 + g];
                pipe[s][1] = mylv[tl * 8 + 4 + g];
                if (u == 0) {
                    e0 = dscale(e0, sf);
                    e1 = dscale(e1, sf);
                    tote += pend;
                }
                STEP(e0, e1);
                if (u == 3) RESCALE();
            }
        }
    } else {
        // boundary chunk: per-step fold + rescale
        for (int tau = 0; tau < count; ++tau) {
            f32x4 e0 = mylv[(tau + shift) * 8 + g];
            f32x4 e1 = mylv[(tau + shift) * 8 + 4 + g];
            e0 = dscale(e0, sf);
            e1 = dscale(e1, sf);
            tote += pend;
            STEP(e0, e1);
            RESCALE();
        }
    }

    // store bf16 col-major: dword idx = col*16 + row/2 (RNE pack, once)
    unsigned int* outP = Pout + ((size_t)b * NCH + c) * 512;
#pragma unroll
    for (int p = 0; p < 2; ++p) {
        int q = 2 * p;
        outP[n * 16        + (4 * g + q) / 2]      = pk_pair(C00[q], C00[q + 1]);
        outP[(16 + n) * 16 + (4 * g + q) / 2]      = pk_pair(C01[q], C01[q + 1]);
        outP[n * 16        + (16 + 4 * g + q) / 2] = pk_pair(C10[q], C10[q + 1]);
        outP[(16 + n) * 16 + (16 + 4 * g + q) / 2] = pk_pair(C11[q], C11[q + 1]);
    }
    if (lane == 0) toteOut[b * NCH + c] = tote;
}

// ---------------- K2: chain chunk matrices through alpha ------------------
template<int NCH, int CHS>
__global__ __launch_bounds__(64) void crf_combine_kernel(
    const float* __restrict__ emissions,
    const int*   __restrict__ lengths32,
    const float* __restrict__ head_t,
    const float* __restrict__ last_t,
    const unsigned short* __restrict__ Pbuf,  // [B][NCH][1024] bf16 col-major
    const int*   __restrict__ toteBuf,
    float*       __restrict__ out)
{
    const int b    = blockIdx.x;
    const int lane = threadIdx.x;
    const int j    = lane & 31;

    const int len = read_len(lengths32, b);
    int nAlive = (len - 1 + CHS - 1) / CHS;
    if (nAlive > NCH) nAlive = NCH;

    float alpha = __expf(head_t[j] + emissions[(size_t)b * TDIM * KDIM + j]);
    int tote = 0;

    const char* base = (const char*)(Pbuf + (size_t)b * NCH * 1024);

    auto LOADC = [&](int cix, uint4 dst[4]) {
        int cc = cix < NCH ? cix : NCH - 1;
        const uint4* pc = (const uint4*)(base + (size_t)cc * 2048 + (size_t)j * 64);
#pragma unroll
        for (int w = 0; w < 4; ++w) dst[w] = pc[w];
    };

    uint4 cur[4], nx1[4];
    LOADC(0, cur);
    LOADC(1, nx1);

    for (int cix = 0; cix < nAlive; ++cix) {
        uint4 nx2[4];
        LOADC(cix + 2, nx2);

        float a0 = 0.0f, a1 = 0.0f;
#pragma unroll
        for (int w = 0; w < 4; ++w) {
            unsigned d[4] = {cur[w].x, cur[w].y, cur[w].z, cur[w].w};
#pragma unroll
            for (int h = 0; h < 4; ++h) {
                int r = w * 8 + h * 2;
                float plo = __uint_as_float(d[h] << 16);           // row r,   col j
                float phi = __uint_as_float(d[h] & 0xffff0000u);   // row r+1, col j
                float al  = __int_as_float(__builtin_amdgcn_readlane(__float_as_int(alpha), r));
                float ah  = __int_as_float(__builtin_amdgcn_readlane(__float_as_int(alpha), r + 1));
                a0 = fmaf(plo, al, a0);
                a1 = fmaf(phi, ah, a1);
            }
        }
        float acc = a0 + a1;
        int bits = __builtin_amdgcn_readfirstlane(__float_as_int(acc));
        int s = ((bits >> 23) & 255) - 127;
        alpha = acc * __uint_as_float((unsigned)(127 - s) << 23);
        tote += s + toteBuf[b * NCH + cix];
#pragma unroll
        for (int w = 0; w < 4; ++w) { cur[w] = nx1[w]; nx1[w] = nx2[w]; }
    }

    float pp = alpha * __expf(last_t[j]);
#pragma unroll
    for (int mm = 16; mm >= 1; mm >>= 1)
        pp += __shfl_xor(pp, mm, 64);

    if (lane == 0)
        out[b] = __logf(pp) + (float)tote * 0.69314718055994531f;
}

extern "C" void kernel_launch(void* const* d_in, const int* in_sizes, int n_in,
                              void* d_out, int out_size, void* d_ws, size_t ws_size,
                              hipStream_t stream)
{
    const float* emissions   = (const float*)d_in[0];
    const int*   lengths     = (const int*)d_in[1];
    const float* transitions = (const float*)d_in[2];
    const float* head_t      = (const float*)d_in[3];
    const float* last_t      = (const float*)d_in[4];
    float* out = (float*)d_out;
    const int B = out_size;  // 512

    unsigned int* Pbuf = (unsigned int*)d_ws;

    const size_t need16 = (size_t)B * 16 * 2048 + (size_t)B * 16 * 4;
    if (ws_size >= need16) {
        int* toteBf = (int*)((char*)d_ws + (size_t)B * 16 * 2048);
        dim3 g1(4, B);    // 4 blocks x 4 waves = 16 chunks of 64 steps
        crf_chunk_kernel<64, 16><<<g1, 256, 0, stream>>>(emissions, lengths, transitions, Pbuf, toteBf);
        crf_combine_kernel<16, 64><<<B, 64, 0, stream>>>(emissions, lengths, head_t, last_t,
                                                         (const unsigned short*)Pbuf, toteBf, out);
    } else {
        int* toteBf = (int*)((char*)d_ws + (size_t)B * 8 * 2048);
        dim3 g1(2, B);    // 2 blocks x 4 waves = 8 chunks of 128 steps
        crf_chunk_kernel<128, 8><<<g1, 256, 0, stream>>>(emissions, lengths, transitions, Pbuf, toteBf);
        crf_combine_kernel<8, 128><<<B, 64, 0, stream>>>(emissions, lengths, head_t, last_t,
                                                         (const unsigned short*)Pbuf, toteBf, out);
    }
}

// Round 19
// 52.096 us; speedup vs baseline: 1.5122x; 1.0527x over previous
//
#include <hip/hip_runtime.h>
#include <hip/hip_bf16.h>

#define TDIM 1024
#define KDIM 32

typedef short bf16x8 __attribute__((ext_vector_type(8)));
typedef float f32x4  __attribute__((ext_vector_type(4)));
typedef float f32x2  __attribute__((ext_vector_type(2)));

// RNE-ish pack (round-half-up): 3 VALU. Off the hot loop only.
__device__ __forceinline__ unsigned pk_pair(float lo, float hi) {
    unsigned ul = __float_as_uint(lo) + 0x8000u;
    unsigned uh = __float_as_uint(hi) + 0x8000u;
    return __builtin_amdgcn_perm(uh, ul, 0x07060302u);
}
// truncating pack: 1 VALU. Hot loop (bias ~-0.1%/use; ledger-safe, R14-verified).
__device__ __forceinline__ unsigned tk_pair(float lo, float hi) {
    return __builtin_amdgcn_perm(__float_as_uint(hi), __float_as_uint(lo), 0x07060302u);
}
__device__ __forceinline__ bf16x8 pk8(f32x4 lo, f32x4 hi) {
    union { unsigned u[4]; bf16x8 v; } x;
    x.u[0] = pk_pair(lo[0], lo[1]); x.u[1] = pk_pair(lo[2], lo[3]);
    x.u[2] = pk_pair(hi[0], hi[1]); x.u[3] = pk_pair(hi[2], hi[3]);
    return x.v;
}
__device__ __forceinline__ bf16x8 tk8(f32x4 lo, f32x4 hi) {
    union { unsigned u[4]; bf16x8 v; } x;
    x.u[0] = tk_pair(lo[0], lo[1]); x.u[1] = tk_pair(lo[2], lo[3]);
    x.u[2] = tk_pair(hi[0], hi[1]); x.u[3] = tk_pair(hi[2], hi[3]);
    return x.v;
}
// f32 elementwise muls as <2 x float> so ISel can form v_pk_mul_f32
__device__ __forceinline__ f32x4 dmul(f32x4 c, f32x4 e) {
    union U { f32x4 v; f32x2 h[2]; };
    U uc, ue, r; uc.v = c; ue.v = e;
    r.h[0] = uc.h[0] * ue.h[0];
    r.h[1] = uc.h[1] * ue.h[1];
    return r.v;
}
__device__ __forceinline__ f32x4 dscale(f32x4 c, float s) {
    union U { f32x4 v; f32x2 h[2]; };
    U uc, r; uc.v = c;
    f32x2 sv = {s, s};
    r.h[0] = uc.h[0] * sv;
    r.h[1] = uc.h[1] * sv;
    return r.v;
}

__device__ __forceinline__ int read_len(const int* __restrict__ lengths32, int b) {
    // int64 little-endian: int32 view at odd index 1 is high word of lengths[0] == 0.
    // int32: lengths[1] in [1,1024], never 0.  (verified rounds 1-18)
    const bool is64 = (lengths32[1] == 0);
    int len = is64 ? lengths32[2 * b] : lengths32[b];
    return len < 1 ? 1 : (len > TDIM ? TDIM : len);
}

// ---------------- K1: per-(batch, chunk) 32x32 product matrix -------------
// R16 hot loop (best: static A, B = trunc-pack(d (.) C), 8 pk-mul + 8 perm
// + 4 MFMA). R19 change: 8 waves/block (512 thr, 64KB LDS) -> 2 resident
// blocks/CU = 16 waves/CU, halved block count (R18 diagnosis: CUs held only
// ~1 block -> block residency/dispatch limited, not chain latency).
template<int CHS, int NCH, int WPB>
__global__ __launch_bounds__(64 * WPB) void crf_chunk_kernel(
    const float* __restrict__ emissions,    // [B, T, K]
    const int*   __restrict__ lengths32,
    const float* __restrict__ transitions,  // [K, K]
    unsigned int* __restrict__ Pout,        // [B][NCH][1024] bf16 as 512 dwords
    int*          __restrict__ toteOut)     // [B][NCH]
{
    __shared__ float lds_all[WPB][CHS * KDIM];
    const int wid  = threadIdx.x >> 6;
    const int lane = threadIdx.x & 63;
    const int n    = lane & 15;
    const int g    = (lane >> 4) & 3;
    const int c    = blockIdx.x * WPB + wid;
    const int b    = blockIdx.y;

    const int len = read_len(lengths32, b);
    const int t0  = 1 + c * CHS;
    int count = len - t0; count = count > CHS ? CHS : count;
    if (count <= 0) return;                  // dead chunk

    // ---- stage CHS emission rows into this wave's LDS slice (async DMA) ----
    int base_t = t0, shift = 0;
    if (t0 + CHS > TDIM) { base_t = TDIM - CHS; shift = t0 - base_t; }
    const float* src = emissions + ((size_t)b * TDIM + base_t) * KDIM;
    float* myl = lds_all[wid];
    constexpr int NSEG = CHS * KDIM / 256;   // 1KB segments
#pragma unroll
    for (int s = 0; s < NSEG; ++s)
        __builtin_amdgcn_global_load_lds(
            (const __attribute__((address_space(1))) void*)(src + s * 256 + lane * 4),
            (__attribute__((address_space(3))) void*)(myl + s * 256), 16, 0, 0);

    // static A operand: bf16(E^T), element e <-> contraction row rho(g,e)
    f32x4 Ef00, Ef01, Ef10, Ef11;
#pragma unroll
    for (int e = 0; e < 4; ++e) {
        Ef00[e] = __expf(transitions[(4 * g + e) * KDIM + n]);
        Ef01[e] = __expf(transitions[(16 + 4 * g + e) * KDIM + n]);
        Ef10[e] = __expf(transitions[(4 * g + e) * KDIM + 16 + n]);
        Ef11[e] = __expf(transitions[(16 + 4 * g + e) * KDIM + 16 + n]);
    }
    const bf16x8 A0 = pk8(Ef00, Ef01);   // rows n      (RNE: reused every step)
    const bf16x8 A1 = pk8(Ef10, Ef11);   // rows 16+n

    asm volatile("s_waitcnt vmcnt(0)" ::: "memory");
    __builtin_amdgcn_sched_barrier(0);

    // ---- exp pre-pass in place (per-wave slice) ----
    f32x4* mylv = (f32x4*)myl;
#pragma unroll
    for (int r = 0; r < NSEG; ++r) {
        f32x4 v = mylv[r * 64 + lane];
#pragma unroll
        for (int e = 0; e < 4; ++e) v[e] = __expf(v[e]);
        mylv[r * 64 + lane] = v;
    }
    asm volatile("s_waitcnt lgkmcnt(0)" ::: "memory");
    __builtin_amdgcn_sched_barrier(0);

    // ---- running product in C-frags ----
    f32x4 C00, C01, C10, C11;
#pragma unroll
    for (int q = 0; q < 4; ++q) {
        float d = (4 * g + q == n) ? 1.0f : 0.0f;
        C00[q] = d; C11[q] = d; C01[q] = 0.0f; C10[q] = 0.0f;
    }
    float sf = 1.0f; int pend = 0, tote = 0;
    const f32x4 zero = {0.0f, 0.0f, 0.0f, 0.0f};

    // d values for this lane group: e0 = d[4g..4g+3], e1 = d[16+4g..16+4g+3]
    // B0 = trunc(e0 (.) C00, e1 (.) C10), B1 = trunc(e0 (.) C01, e1 (.) C11)
    auto STEP = [&](const f32x4& e0, const f32x4& e1) {
        f32x4 t0v = dmul(C00, e0), t1v = dmul(C10, e1);
        f32x4 t2v = dmul(C01, e0), t3v = dmul(C11, e1);
        bf16x8 B0 = tk8(t0v, t1v), B1 = tk8(t2v, t3v);
        C00 = __builtin_amdgcn_mfma_f32_16x16x32_bf16(A0, B0, zero, 0, 0, 0);
        C01 = __builtin_amdgcn_mfma_f32_16x16x32_bf16(A0, B1, zero, 0, 0, 0);
        C10 = __builtin_amdgcn_mfma_f32_16x16x32_bf16(A1, B0, zero, 0, 0, 0);
        C11 = __builtin_amdgcn_mfma_f32_16x16x32_bf16(A1, B1, zero, 0, 0, 0);
    };
    auto RESCALE = [&]() {
        int bits = __builtin_amdgcn_readfirstlane(__float_as_int(C00[0]));
        pend = ((bits >> 23) & 255) - 127;
        sf = __uint_as_float((unsigned)(127 - pend) << 23);
    };

    if (count == CHS) {
        // depth-2 LDS read pipeline, static slot = u&1
        f32x4 pipe[2][2];
        pipe[0][0] = mylv[0 * 8 + g]; pipe[0][1] = mylv[0 * 8 + 4 + g];
        pipe[1][0] = mylv[1 * 8 + g]; pipe[1][1] = mylv[1 * 8 + 4 + g];
        constexpr int NQ = CHS / 4;
        for (int tq = 0; tq < NQ; ++tq) {
#pragma unroll
            for (int u = 0; u < 4; ++u) {
                const int s = u & 1;
                f32x4 e0 = pipe[s][0], e1 = pipe[s][1];
                int tl = 4 * tq + u + 2; if (tl > CHS - 1) tl = CHS - 1;
                pipe[s][0] = mylv[tl * 8 + g];
                pipe[s][1] = mylv[tl * 8 + 4 + g];
                if (u == 0) {
                    e0 = dscale(e0, sf);
                    e1 = dscale(e1, sf);
                    tote += pend;
                }
                STEP(e0, e1);
                if (u == 3) RESCALE();
            }
        }
    } else {
        // boundary chunk: per-step fold + rescale
        for (int tau = 0; tau < count; ++tau) {
            f32x4 e0 = mylv[(tau + shift) * 8 + g];
            f32x4 e1 = mylv[(tau + shift) * 8 + 4 + g];
            e0 = dscale(e0, sf);
            e1 = dscale(e1, sf);
            tote += pend;
            STEP(e0, e1);
            RESCALE();
        }
    }

    // store bf16 col-major: dword idx = col*16 + row/2 (RNE pack, once)
    unsigned int* outP = Pout + ((size_t)b * NCH + c) * 512;
#pragma unroll
    for (int p = 0; p < 2; ++p) {
        int q = 2 * p;
        outP[n * 16        + (4 * g + q) / 2]      = pk_pair(C00[q], C00[q + 1]);
        outP[(16 + n) * 16 + (4 * g + q) / 2]      = pk_pair(C01[q], C01[q + 1]);
        outP[n * 16        + (16 + 4 * g + q) / 2] = pk_pair(C10[q], C10[q + 1]);
        outP[(16 + n) * 16 + (16 + 4 * g + q) / 2] = pk_pair(C11[q], C11[q + 1]);
    }
    if (lane == 0) toteOut[b * NCH + c] = tote;
}

// ---------------- K2: chain chunk matrices through alpha ------------------
template<int NCH, int CHS>
__global__ __launch_bounds__(64) void crf_combine_kernel(
    const float* __restrict__ emissions,
    const int*   __restrict__ lengths32,
    const float* __restrict__ head_t,
    const float* __restrict__ last_t,
    const unsigned short* __restrict__ Pbuf,  // [B][NCH][1024] bf16 col-major
    const int*   __restrict__ toteBuf,
    float*       __restrict__ out)
{
    const int b    = blockIdx.x;
    const int lane = threadIdx.x;
    const int j    = lane & 31;

    const int len = read_len(lengths32, b);
    int nAlive = (len - 1 + CHS - 1) / CHS;
    if (nAlive > NCH) nAlive = NCH;

    float alpha = __expf(head_t[j] + emissions[(size_t)b * TDIM * KDIM + j]);
    int tote = 0;

    const char* base = (const char*)(Pbuf + (size_t)b * NCH * 1024);

    auto LOADC = [&](int cix, uint4 dst[4]) {
        int cc = cix < NCH ? cix : NCH - 1;
        const uint4* pc = (const uint4*)(base + (size_t)cc * 2048 + (size_t)j * 64);
#pragma unroll
        for (int w = 0; w < 4; ++w) dst[w] = pc[w];
    };

    uint4 cur[4], nx1[4];
    LOADC(0, cur);
    LOADC(1, nx1);

    for (int cix = 0; cix < nAlive; ++cix) {
        uint4 nx2[4];
        LOADC(cix + 2, nx2);

        float a0 = 0.0f, a1 = 0.0f;
#pragma unroll
        for (int w = 0; w < 4; ++w) {
            unsigned d[4] = {cur[w].x, cur[w].y, cur[w].z, cur[w].w};
#pragma unroll
            for (int h = 0; h < 4; ++h) {
                int r = w * 8 + h * 2;
                float plo = __uint_as_float(d[h] << 16);           // row r,   col j
                float phi = __uint_as_float(d[h] & 0xffff0000u);   // row r+1, col j
                float al  = __int_as_float(__builtin_amdgcn_readlane(__float_as_int(alpha), r));
                float ah  = __int_as_float(__builtin_amdgcn_readlane(__float_as_int(alpha), r + 1));
                a0 = fmaf(plo, al, a0);
                a1 = fmaf(phi, ah, a1);
            }
        }
        float acc = a0 + a1;
        int bits = __builtin_amdgcn_readfirstlane(__float_as_int(acc));
        int s = ((bits >> 23) & 255) - 127;
        alpha = acc * __uint_as_float((unsigned)(127 - s) << 23);
        tote += s + toteBuf[b * NCH + cix];
#pragma unroll
        for (int w = 0; w < 4; ++w) { cur[w] = nx1[w]; nx1[w] = nx2[w]; }
    }

    float pp = alpha * __expf(last_t[j]);
#pragma unroll
    for (int mm = 16; mm >= 1; mm >>= 1)
        pp += __shfl_xor(pp, mm, 64);

    if (lane == 0)
        out[b] = __logf(pp) + (float)tote * 0.69314718055994531f;
}

extern "C" void kernel_launch(void* const* d_in, const int* in_sizes, int n_in,
                              void* d_out, int out_size, void* d_ws, size_t ws_size,
                              hipStream_t stream)
{
    const float* emissions   = (const float*)d_in[0];
    const int*   lengths     = (const int*)d_in[1];
    const float* transitions = (const float*)d_in[2];
    const float* head_t      = (const float*)d_in[3];
    const float* last_t      = (const float*)d_in[4];
    float* out = (float*)d_out;
    const int B = out_size;  // 512

    unsigned int* Pbuf = (unsigned int*)d_ws;

    const size_t need16 = (size_t)B * 16 * 2048 + (size_t)B * 16 * 4;
    if (ws_size >= need16) {
        int* toteBf = (int*)((char*)d_ws + (size_t)B * 16 * 2048);
        // 8 waves/block (512 thr, 64KB LDS -> 2 blocks/CU, 16 waves/CU);
        // 2 blocks x 8 chunks = 16 chunks of 64 steps
        dim3 g1(2, B);
        crf_chunk_kernel<64, 16, 8><<<g1, 512, 0, stream>>>(emissions, lengths, transitions, Pbuf, toteBf);
        crf_combine_kernel<16, 64><<<B, 64, 0, stream>>>(emissions, lengths, head_t, last_t,
                                                         (const unsigned short*)Pbuf, toteBf, out);
    } else {
        int* toteBf = (int*)((char*)d_ws + (size_t)B * 8 * 2048);
        dim3 g1(1, B);    // 1 block x 8 waves = 8 chunks of 128 steps
        crf_chunk_kernel<128, 8, 8><<<g1, 512, 0, stream>>>(emissions, lengths, transitions, Pbuf, toteBf);
        crf_combine_kernel<8, 128><<<B, 64, 0, stream>>>(emissions, lengths, head_t, last_t,
                                                         (const unsigned short*)Pbuf, toteBf, out);
    }
}

// Round 20
// 50.929 us; speedup vs baseline: 1.5469x; 1.0229x over previous
//
#include <hip/hip_runtime.h>
#include <hip/hip_bf16.h>

#define TDIM 1024
#define KDIM 32

typedef short bf16x8 __attribute__((ext_vector_type(8)));
typedef float f32x4  __attribute__((ext_vector_type(4)));
typedef float f32x2  __attribute__((ext_vector_type(2)));

// RNE-ish pack (round-half-up): 3 VALU. Off the hot loop only.
__device__ __forceinline__ unsigned pk_pair(float lo, float hi) {
    unsigned ul = __float_as_uint(lo) + 0x8000u;
    unsigned uh = __float_as_uint(hi) + 0x8000u;
    return __builtin_amdgcn_perm(uh, ul, 0x07060302u);
}
// truncating pack: 1 VALU. Hot loop (bias ~-0.1%/use; ledger-safe, R14-verified).
__device__ __forceinline__ unsigned tk_pair(float lo, float hi) {
    return __builtin_amdgcn_perm(__float_as_uint(hi), __float_as_uint(lo), 0x07060302u);
}
__device__ __forceinline__ bf16x8 pk8(f32x4 lo, f32x4 hi) {
    union { unsigned u[4]; bf16x8 v; } x;
    x.u[0] = pk_pair(lo[0], lo[1]); x.u[1] = pk_pair(lo[2], lo[3]);
    x.u[2] = pk_pair(hi[0], hi[1]); x.u[3] = pk_pair(hi[2], hi[3]);
    return x.v;
}
__device__ __forceinline__ bf16x8 tk8(f32x4 lo, f32x4 hi) {
    union { unsigned u[4]; bf16x8 v; } x;
    x.u[0] = tk_pair(lo[0], lo[1]); x.u[1] = tk_pair(lo[2], lo[3]);
    x.u[2] = tk_pair(hi[0], hi[1]); x.u[3] = tk_pair(hi[2], hi[3]);
    return x.v;
}
// f32 elementwise muls as <2 x float> so ISel can form v_pk_mul_f32
__device__ __forceinline__ f32x4 dmul(f32x4 c, f32x4 e) {
    union U { f32x4 v; f32x2 h[2]; };
    U uc, ue, r; uc.v = c; ue.v = e;
    r.h[0] = uc.h[0] * ue.h[0];
    r.h[1] = uc.h[1] * ue.h[1];
    return r.v;
}
__device__ __forceinline__ f32x4 dscale(f32x4 c, float s) {
    union U { f32x4 v; f32x2 h[2]; };
    U uc, r; uc.v = c;
    f32x2 sv = {s, s};
    r.h[0] = uc.h[0] * sv;
    r.h[1] = uc.h[1] * sv;
    return r.v;
}

__device__ __forceinline__ int read_len(const int* __restrict__ lengths32, int b) {
    // int64 little-endian: int32 view at odd index 1 is high word of lengths[0] == 0.
    // int32: lengths[1] in [1,1024], never 0.  (verified rounds 1-19)
    const bool is64 = (lengths32[1] == 0);
    int len = is64 ? lengths32[2 * b] : lengths32[b];
    return len < 1 ? 1 : (len > TDIM ? TDIM : len);
}

// ---------------- K1: per-(batch, chunk) 32x32 product matrix -------------
// R16 hot loop (best verified: static A = bf16(E^T), B = trunc-pack(d (.) C),
// 8 pk-mul + 8 perm + 4 MFMA). R20: de-clamped main loop (prefetch index
// provably in-bounds; final group prefetches only its first 2 steps) — the
// count model (R14-R19: dur ~ inst/step at ~0.31 inst/cyc/CU) says ~-8%.
template<int CHS, int NCH>
__global__ __launch_bounds__(256, 4) void crf_chunk_kernel(
    const float* __restrict__ emissions,    // [B, T, K]
    const int*   __restrict__ lengths32,
    const float* __restrict__ transitions,  // [K, K]
    unsigned int* __restrict__ Pout,        // [B][NCH][1024] bf16 as 512 dwords
    int*          __restrict__ toteOut)     // [B][NCH]
{
    __shared__ float lds_all[4][CHS * KDIM];
    const int wid  = threadIdx.x >> 6;
    const int lane = threadIdx.x & 63;
    const int n    = lane & 15;
    const int g    = (lane >> 4) & 3;
    const int c    = blockIdx.x * 4 + wid;
    const int b    = blockIdx.y;

    const int len = read_len(lengths32, b);
    const int t0  = 1 + c * CHS;
    int count = len - t0; count = count > CHS ? CHS : count;
    if (count <= 0) return;                  // dead chunk

    // ---- stage CHS emission rows into this wave's LDS slice (async DMA) ----
    int base_t = t0, shift = 0;
    if (t0 + CHS > TDIM) { base_t = TDIM - CHS; shift = t0 - base_t; }
    const float* src = emissions + ((size_t)b * TDIM + base_t) * KDIM;
    float* myl = lds_all[wid];
    constexpr int NSEG = CHS * KDIM / 256;   // 1KB segments
#pragma unroll
    for (int s = 0; s < NSEG; ++s)
        __builtin_amdgcn_global_load_lds(
            (const __attribute__((address_space(1))) void*)(src + s * 256 + lane * 4),
            (__attribute__((address_space(3))) void*)(myl + s * 256), 16, 0, 0);

    // static A operand: bf16(E^T), element e <-> contraction row rho(g,e)
    f32x4 Ef00, Ef01, Ef10, Ef11;
#pragma unroll
    for (int e = 0; e < 4; ++e) {
        Ef00[e] = __expf(transitions[(4 * g + e) * KDIM + n]);
        Ef01[e] = __expf(transitions[(16 + 4 * g + e) * KDIM + n]);
        Ef10[e] = __expf(transitions[(4 * g + e) * KDIM + 16 + n]);
        Ef11[e] = __expf(transitions[(16 + 4 * g + e) * KDIM + 16 + n]);
    }
    const bf16x8 A0 = pk8(Ef00, Ef01);   // rows n      (RNE: reused every step)
    const bf16x8 A1 = pk8(Ef10, Ef11);   // rows 16+n

    asm volatile("s_waitcnt vmcnt(0)" ::: "memory");
    __builtin_amdgcn_sched_barrier(0);

    // ---- exp pre-pass in place (per-wave slice) ----
    f32x4* mylv = (f32x4*)myl;
#pragma unroll
    for (int r = 0; r < NSEG; ++r) {
        f32x4 v = mylv[r * 64 + lane];
#pragma unroll
        for (int e = 0; e < 4; ++e) v[e] = __expf(v[e]);
        mylv[r * 64 + lane] = v;
    }
    asm volatile("s_waitcnt lgkmcnt(0)" ::: "memory");
    __builtin_amdgcn_sched_barrier(0);

    // ---- running product in C-frags ----
    f32x4 C00, C01, C10, C11;
#pragma unroll
    for (int q = 0; q < 4; ++q) {
        float d = (4 * g + q == n) ? 1.0f : 0.0f;
        C00[q] = d; C11[q] = d; C01[q] = 0.0f; C10[q] = 0.0f;
    }
    float sf = 1.0f; int pend = 0, tote = 0;
    const f32x4 zero = {0.0f, 0.0f, 0.0f, 0.0f};

    auto STEP = [&](const f32x4& e0, const f32x4& e1) {
        f32x4 t0v = dmul(C00, e0), t1v = dmul(C10, e1);
        f32x4 t2v = dmul(C01, e0), t3v = dmul(C11, e1);
        bf16x8 B0 = tk8(t0v, t1v), B1 = tk8(t2v, t3v);
        C00 = __builtin_amdgcn_mfma_f32_16x16x32_bf16(A0, B0, zero, 0, 0, 0);
        C01 = __builtin_amdgcn_mfma_f32_16x16x32_bf16(A0, B1, zero, 0, 0, 0);
        C10 = __builtin_amdgcn_mfma_f32_16x16x32_bf16(A1, B0, zero, 0, 0, 0);
        C11 = __builtin_amdgcn_mfma_f32_16x16x32_bf16(A1, B1, zero, 0, 0, 0);
    };
    auto RESCALE = [&]() {
        int bits = __builtin_amdgcn_readfirstlane(__float_as_int(C00[0]));
        pend = ((bits >> 23) & 255) - 127;
        sf = __uint_as_float((unsigned)(127 - pend) << 23);
    };

    if (count == CHS) {
        // depth-2 LDS read pipeline, static slot = u&1; main body needs no
        // bounds clamp (tl <= CHS-3); final group prefetches only u<2.
        f32x4 pipe[2][2];
        pipe[0][0] = mylv[0 * 8 + g]; pipe[0][1] = mylv[0 * 8 + 4 + g];
        pipe[1][0] = mylv[1 * 8 + g]; pipe[1][1] = mylv[1 * 8 + 4 + g];
        constexpr int NQ = CHS / 4;
        for (int tq = 0; tq < NQ - 1; ++tq) {
#pragma unroll
            for (int u = 0; u < 4; ++u) {
                const int s = u & 1;
                f32x4 e0 = pipe[s][0], e1 = pipe[s][1];
                const int tl = 4 * tq + u + 2;     // <= CHS-3: in-bounds
                pipe[s][0] = mylv[tl * 8 + g];
                pipe[s][1] = mylv[tl * 8 + 4 + g];
                if (u == 0) {
                    e0 = dscale(e0, sf);
                    e1 = dscale(e1, sf);
                    tote += pend;
                }
                STEP(e0, e1);
                if (u == 3) RESCALE();
            }
        }
        // final group (steps CHS-4..CHS-1): prefetch only steps CHS-2, CHS-1
#pragma unroll
        for (int u = 0; u < 4; ++u) {
            const int s = u & 1;
            f32x4 e0 = pipe[s][0], e1 = pipe[s][1];
            if (u < 2) {
                const int tl = 4 * (NQ - 1) + u + 2;   // CHS-2, CHS-1
                pipe[s][0] = mylv[tl * 8 + g];
                pipe[s][1] = mylv[tl * 8 + 4 + g];
            }
            if (u == 0) {
                e0 = dscale(e0, sf);
                e1 = dscale(e1, sf);
                tote += pend;
            }
            STEP(e0, e1);
            if (u == 3) RESCALE();
        }
    } else {
        // boundary chunk: per-step fold + rescale
        for (int tau = 0; tau < count; ++tau) {
            f32x4 e0 = mylv[(tau + shift) * 8 + g];
            f32x4 e1 = mylv[(tau + shift) * 8 + 4 + g];
            e0 = dscale(e0, sf);
            e1 = dscale(e1, sf);
            tote += pend;
            STEP(e0, e1);
            RESCALE();
        }
    }

    // store bf16 col-major: dword idx = col*16 + row/2 (RNE pack, once)
    unsigned int* outP = Pout + ((size_t)b * NCH + c) * 512;
#pragma unroll
    for (int p = 0; p < 2; ++p) {
        int q = 2 * p;
        outP[n * 16        + (4 * g + q) / 2]      = pk_pair(C00[q], C00[q + 1]);
        outP[(16 + n) * 16 + (4 * g + q) / 2]      = pk_pair(C01[q], C01[q + 1]);
        outP[n * 16        + (16 + 4 * g + q) / 2] = pk_pair(C10[q], C10[q + 1]);
        outP[(16 + n) * 16 + (16 + 4 * g + q) / 2] = pk_pair(C11[q], C11[q + 1]);
    }
    if (lane == 0) toteOut[b * NCH + c] = tote;
}

// ---------------- K2: chain chunk matrices through alpha ------------------
// Two batches per 128-thread block (wave 0 -> 2*bx, wave 1 -> 2*bx+1).
template<int NCH, int CHS>
__global__ __launch_bounds__(128) void crf_combine_kernel(
    const float* __restrict__ emissions,
    const int*   __restrict__ lengths32,
    const float* __restrict__ head_t,
    const float* __restrict__ last_t,
    const unsigned short* __restrict__ Pbuf,  // [B][NCH][1024] bf16 col-major
    const int*   __restrict__ toteBuf,
    float*       __restrict__ out,
    int B)
{
    const int wid  = threadIdx.x >> 6;
    const int b    = blockIdx.x * 2 + wid;
    if (b >= B) return;
    const int lane = threadIdx.x & 63;
    const int j    = lane & 31;

    const int len = read_len(lengths32, b);
    int nAlive = (len - 1 + CHS - 1) / CHS;
    if (nAlive > NCH) nAlive = NCH;

    float alpha = __expf(head_t[j] + emissions[(size_t)b * TDIM * KDIM + j]);
    int tote = 0;

    const char* base = (const char*)(Pbuf + (size_t)b * NCH * 1024);

    auto LOADC = [&](int cix, uint4 dst[4]) {
        int cc = cix < NCH ? cix : NCH - 1;
        const uint4* pc = (const uint4*)(base + (size_t)cc * 2048 + (size_t)j * 64);
#pragma unroll
        for (int w = 0; w < 4; ++w) dst[w] = pc[w];
    };

    uint4 cur[4], nx1[4];
    LOADC(0, cur);
    LOADC(1, nx1);

    for (int cix = 0; cix < nAlive; ++cix) {
        uint4 nx2[4];
        LOADC(cix + 2, nx2);

        float a0 = 0.0f, a1 = 0.0f;
#pragma unroll
        for (int w = 0; w < 4; ++w) {
            unsigned d[4] = {cur[w].x, cur[w].y, cur[w].z, cur[w].w};
#pragma unroll
            for (int h = 0; h < 4; ++h) {
                int r = w * 8 + h * 2;
                float plo = __uint_as_float(d[h] << 16);           // row r,   col j
                float phi = __uint_as_float(d[h] & 0xffff0000u);   // row r+1, col j
                float al  = __int_as_float(__builtin_amdgcn_readlane(__float_as_int(alpha), r));
                float ah  = __int_as_float(__builtin_amdgcn_readlane(__float_as_int(alpha), r + 1));
                a0 = fmaf(plo, al, a0);
                a1 = fmaf(phi, ah, a1);
            }
        }
        float acc = a0 + a1;
        int bits = __builtin_amdgcn_readfirstlane(__float_as_int(acc));
        int s = ((bits >> 23) & 255) - 127;
        alpha = acc * __uint_as_float((unsigned)(127 - s) << 23);
        tote += s + toteBuf[b * NCH + cix];
#pragma unroll
        for (int w = 0; w < 4; ++w) { cur[w] = nx1[w]; nx1[w] = nx2[w]; }
    }

    float pp = alpha * __expf(last_t[j]);
#pragma unroll
    for (int mm = 16; mm >= 1; mm >>= 1)
        pp += __shfl_xor(pp, mm, 64);

    if (lane == 0)
        out[b] = __logf(pp) + (float)tote * 0.69314718055994531f;
}

extern "C" void kernel_launch(void* const* d_in, const int* in_sizes, int n_in,
                              void* d_out, int out_size, void* d_ws, size_t ws_size,
                              hipStream_t stream)
{
    const float* emissions   = (const float*)d_in[0];
    const int*   lengths     = (const int*)d_in[1];
    const float* transitions = (const float*)d_in[2];
    const float* head_t      = (const float*)d_in[3];
    const float* last_t      = (const float*)d_in[4];
    float* out = (float*)d_out;
    const int B = out_size;  // 512

    unsigned int* Pbuf = (unsigned int*)d_ws;

    const size_t need16 = (size_t)B * 16 * 2048 + (size_t)B * 16 * 4;
    if (ws_size >= need16) {
        int* toteBf = (int*)((char*)d_ws + (size_t)B * 16 * 2048);
        dim3 g1(4, B);    // 4 blocks x 4 waves = 16 chunks of 64 steps
        crf_chunk_kernel<64, 16><<<g1, 256, 0, stream>>>(emissions, lengths, transitions, Pbuf, toteBf);
        crf_combine_kernel<16, 64><<<(B + 1) / 2, 128, 0, stream>>>(emissions, lengths, head_t, last_t,
                                                                    (const unsigned short*)Pbuf, toteBf, out, B);
    } else {
        int* toteBf = (int*)((char*)d_ws + (size_t)B * 8 * 2048);
        dim3 g1(2, B);    // 2 blocks x 4 waves = 8 chunks of 128 steps
        crf_chunk_kernel<128, 8><<<g1, 256, 0, stream>>>(emissions, lengths, transitions, Pbuf, toteBf);
        crf_combine_kernel<8, 128><<<(B + 1) / 2, 128, 0, stream>>>(emissions, lengths, head_t, last_t,
                                                                    (const unsigned short*)Pbuf, toteBf, out, B);
    }
}